// Round 14
// baseline (102.869 us; speedup 1.0000x reference)
//
#include <hip/hip_runtime.h>

#define NPOS 4096
#define NB   64

typedef __bf16 bf8v __attribute__((ext_vector_type(8)));
typedef float  f4   __attribute__((ext_vector_type(4)));

__device__ __forceinline__ float sigm(float x)   { return 1.0f / (1.0f + __expf(-x)); }
__device__ __forceinline__ float tanh_f(float x) { return 1.0f - 2.0f / (1.0f + __expf(2.0f * x)); }

__device__ __forceinline__ f4 MF(bf8v a, bf8v b, f4 c) {
    return __builtin_amdgcn_mfma_f32_16x16x32_bf16(a, b, c, 0, 0, 0);
}

// async global->LDS, 16B per lane; LDS dest = wave-uniform base + lane*16
__device__ __forceinline__ void gl_lds16(const void* g, void* l) {
    __builtin_amdgcn_global_load_lds(
        (const __attribute__((address_space(1))) void*)g,
        (__attribute__((address_space(3)))       void*)l,
        16, 0, 0);
}

// ---------------- phase-contiguous frag layout in d_ws (1KB frags) ----------------
// (unchanged from R9; PERM layers use k-slot feature kb*32+16*(j>>2)+4*sg+(j&3)
//  so the next layer's B-frag is a lane-local repack of this layer's C regs)
#define NFRAG 211

__global__ __launch_bounds__(64) void prep_kernel(
    const float* __restrict__ pcW1, const float* __restrict__ pcb1, const float* __restrict__ pcW2, const float* __restrict__ pcb2,
    const float* __restrict__ fcW1, const float* __restrict__ fcb1, const float* __restrict__ fcW2, const float* __restrict__ fcb2,
    const float* __restrict__ ycW1, const float* __restrict__ ycb1, const float* __restrict__ ycW2, const float* __restrict__ ycb2,
    const float* __restrict__ ndW1, const float* __restrict__ ndb1, const float* __restrict__ ndW2, const float* __restrict__ ndb2,
    const float* __restrict__ Wih,  const float* __restrict__ bih,  const float* __restrict__ Whh,  const float* __restrict__ bhh,
    const float* __restrict__ dW1,  const float* __restrict__ db1,  const float* __restrict__ dW2,  const float* __restrict__ db2,
    char* __restrict__ ws)
{
    const int f = blockIdx.x, l = threadIdx.x;
    const int sg = l >> 4, c16 = l & 15;
    char* dst = ws + (size_t)f * 1024 + (size_t)l * 16;

    int kind = 0;                 // 0: bf16 weight frag, 1: f32 bias frag
    const float* W = nullptr; const float* B1 = nullptr; const float* B2 = nullptr;
    int t = 0, kb = 0, ncol = 64, coloff = 0, boff = 0, mlp = 0;
    bool msgmask = false, decw2 = false, db2frag = false, perm = false;

    if (f < 108) {
        const int m = f / 36, r = f % 36;
        const float* W1 = (m == 0 ? pcW1 : (m == 1 ? fcW1 : ycW1));
        const float* W2 = (m == 0 ? pcW2 : (m == 1 ? fcW2 : ycW2));
        const float* b1 = (m == 0 ? pcb1 : (m == 1 ? fcb1 : ycb1));
        const float* b2 = (m == 0 ? pcb2 : (m == 1 ? fcb2 : ycb2));
        if (r < 20)      { W = W1; kb = r >> 2; t = r & 3; msgmask = (kb == 4); mlp = m; }
        else if (r < 28) { W = W2; int rr = r - 20; kb = rr >> 2; t = rr & 3; perm = true; }
        else if (r < 32) { kind = 1; B1 = b1; t = r - 28; }
        else             { kind = 1; B1 = b2; t = r - 32; }
    } else if (f < 132) {
        const int r = f - 108;
        if (r < 8)       { W = ndW1; kb = r >> 2; t = r & 3; perm = true; }
        else if (r < 16) { W = ndW2; int rr = r - 8; kb = rr >> 2; t = rr & 3; perm = true; }
        else if (r < 20) { kind = 1; B1 = ndb1; t = r - 16; }
        else             { kind = 1; B1 = ndb2; t = r - 20; }
    } else if (f < 164) {
        const int r = f - 132; ncol = 192;
        if (r < 8)       { W = Whh; coloff = 128; kb = r >> 2; t = r & 3; }
        else if (r < 16) { W = Wih; coloff = 0;   int rr = r - 8;  kb = rr >> 2; t = rr & 3; perm = true; }
        else if (r < 24) { W = Whh; coloff = 0;   int rr = r - 16; kb = rr >> 2; t = rr & 3; }
        else if (r < 28) { kind = 1; B1 = bhh; boff = 128; t = r - 24; }
        else             { kind = 1; B1 = bih; B2 = bhh; boff = 0; t = r - 28; }
    } else if (f < 196) {
        const int r = f - 164; ncol = 192;
        if (r < 8)       { W = Wih; coloff = 128; kb = r >> 2; t = r & 3; perm = true; }
        else if (r < 16) { W = Wih; coloff = 64;  int rr = r - 8;  kb = rr >> 2; t = rr & 3; perm = true; }
        else if (r < 24) { W = Whh; coloff = 64;  int rr = r - 16; kb = rr >> 2; t = rr & 3; }
        else if (r < 28) { kind = 1; B1 = bih; boff = 128; t = r - 24; }
        else             { kind = 1; B1 = bih; B2 = bhh; boff = 64; t = r - 28; }
    } else {
        const int r = f - 196;
        if (r < 8)       { W = dW1; kb = r >> 2; t = r & 3; perm = true; }
        else if (r < 10) { W = dW2; kb = r - 8; t = 0; decw2 = true; perm = true; }
        else if (r < 14) { kind = 1; B1 = db1; t = r - 10; }
        else             { kind = 1; B1 = db2; t = 0; db2frag = true; }
    }

    if (!kind) {
        const int row = 16 * t + c16;
        bf8v v;
        #pragma unroll
        for (int j = 0; j < 8; ++j) {
            const int k = perm ? (kb * 32 + 16 * (j >> 2) + 4 * sg + (j & 3))
                               : (kb * 32 + sg * 8 + j);
            float x;
            if (msgmask) { const int kk = k - 128 - mlp * 4; x = (kk >= 0 && kk < 4) ? W[(128 + kk) * 64 + row] : 0.f; }
            else if (decw2) { x = (row < 4) ? W[k * 4 + row] : 0.f; }
            else { x = W[k * ncol + coloff + row]; }
            v[j] = (__bf16)x;
        }
        *(bf8v*)dst = v;
    } else {
        f4 o;
        #pragma unroll
        for (int r4 = 0; r4 < 4; ++r4) {
            float x;
            if (db2frag) { x = (sg == 0 && t == 0) ? B1[r4] : 0.f; }
            else {
                const int fi = boff + 16 * t + 4 * sg + r4;
                x = B1[fi]; if (B2) x += B2[fi];
            }
            o[r4] = x;
        }
        *(f4*)dst = o;
    }
}

// ---------------- LDS: double-buffered weight phase buffers ----------------
#define WSTRIDE 36864
#define LDSZ    73728      // 2 x 36 frags x 1KB -> 2 blocks/CU (matches (256,2))

__global__ __launch_bounds__(256, 2) void kgnn_main(
    const float* __restrict__ hx,  const float* __restrict__ pcm,
    const float* __restrict__ fcm, const float* __restrict__ ycm,
    const float* __restrict__ hy,
    const char*  __restrict__ ws,  float* __restrict__ out)
{
    __shared__ __align__(16) char LD[LDSZ];
    char* const bufA = LD;
    char* const bufB = LD + WSTRIDE;
    const int tid  = threadIdx.x;
    const int b    = blockIdx.x >> 5;
    const int tile = blockIdx.x & 31;
    const int n0   = tile * 128;
    const int baseH = b * 64 * NPOS;
    const int baseX = b * 4 * NPOS;

    const int lane = tid & 63, wid = tid >> 6;
    const int s = lane >> 4, q = lane & 15;
    const int Pv[2] = { wid * 32 + q, wid * 32 + 16 + q };
    const int Gn[2] = { n0 + Pv[0], n0 + Pv[1] };

    auto ldTB = [&](const float* __restrict__ T, int gnq, int h) -> bf8v {
        bf8v v;
        #pragma unroll
        for (int j = 0; j < 8; ++j)
            v[j] = (__bf16)T[baseH + (h * 32 + 8 * s + j) * NPOS + gnq];
        return v;
    };
    auto packB = [&](const f4* aa, int h, bool relu) -> bf8v {
        bf8v v;
        #pragma unroll
        for (int j = 0; j < 8; ++j) {
            float x = aa[2 * h + (j >> 2)][j & 3];
            if (relu) x = fmaxf(x, 0.f);
            v[j] = (__bf16)x;
        }
        return v;
    };

    // ---- ALL input-side global B-frags hoisted: ONE latency window at kernel start ----
    bf8v hxn0[2], hxn1[2], msgB[2];
    bf8v eA0[3][2], eA1[3][2];          // [m][cc]: m0=hx[n-1], m1=hx[n+1], m2=hy
    #pragma unroll
    for (int cc = 0; cc < 2; ++cc) {
        const int gm = (Gn[cc] == 0) ? 0 : Gn[cc] - 1;
        const int gp = (Gn[cc] == NPOS - 1) ? NPOS - 1 : Gn[cc] + 1;
        hxn0[cc] = ldTB(hx, Gn[cc], 0);
        hxn1[cc] = ldTB(hx, Gn[cc], 1);
        eA0[0][cc] = ldTB(hx, gm, 0);  eA1[0][cc] = ldTB(hx, gm, 1);
        eA0[1][cc] = ldTB(hx, gp, 0);  eA1[1][cc] = ldTB(hx, gp, 1);
        eA0[2][cc] = ldTB(hy, Gn[cc], 0); eA1[2][cc] = ldTB(hy, Gn[cc], 1);
        #pragma unroll
        for (int j = 0; j < 8; ++j) {
            const int idx = 8 * s + j;
            float x = 0.f;
            if      (idx < 4)  x = pcm[baseX + idx * NPOS + Gn[cc]];
            else if (idx < 8)  x = fcm[baseX + (idx - 4) * NPOS + Gn[cc]];
            else if (idx < 12) x = ycm[baseX + (idx - 8) * NPOS + Gn[cc]];
            msgB[cc][j] = (__bf16)x;
        }
    }

    // async wave-interleaved staging of one phase's frags into an LDS buffer
    auto stageA = [&](char* dstbuf, int gbase, int nf) {
        #pragma unroll
        for (int f0 = 0; f0 < 9; ++f0) {
            const int f = f0 * 4 + wid;
            if (f < nf)
                gl_lds16(ws + ((size_t)(gbase + f) << 10) + ((size_t)lane << 4),
                         dstbuf + (f << 10));
        }
    };

    auto ldAL = [&](const char* base, int fl) -> bf8v {
        return *(const bf8v*)(base + (fl << 10) + (lane << 4));
    };
    auto ldBiasL = [&](const char* base, int fl) -> f4 {
        return *(const f4*)(base + (fl << 10) + (lane << 4));
    };

    stageA(bufA, 0, 36);           // P0 -> A
    __syncthreads();               // drains vmcnt (incl. hoisted input loads)

    // ======== P0/P1/P2: pc / fc / yc MLPs ========
    bf8v sB[2][2];                 // packed bf16 running sum pe+fe+ye
    #pragma unroll
    for (int m = 0; m < 3; ++m) {
        char* cur = (m & 1) ? bufB : bufA;
        char* oth = (m & 1) ? bufA : bufB;
        stageA(oth, (m == 0) ? 36 : (m == 1 ? 72 : 108), (m == 2) ? 24 : 36);   // next phase

        f4 a[2][4];
        #pragma unroll
        for (int t = 0; t < 4; ++t) { f4 bv = ldBiasL(cur, 28 + t); a[0][t] = bv; a[1][t] = bv; }
        #pragma unroll
        for (int t = 0; t < 4; ++t) { bf8v A = ldAL(cur, t);      a[0][t] = MF(A, eA0[m][0], a[0][t]); a[1][t] = MF(A, eA0[m][1], a[1][t]); }
        #pragma unroll
        for (int t = 0; t < 4; ++t) { bf8v A = ldAL(cur, 4 + t);  a[0][t] = MF(A, eA1[m][0], a[0][t]); a[1][t] = MF(A, eA1[m][1], a[1][t]); }
        #pragma unroll
        for (int t = 0; t < 4; ++t) { bf8v A = ldAL(cur, 8 + t);  a[0][t] = MF(A, hxn0[0],   a[0][t]); a[1][t] = MF(A, hxn0[1],   a[1][t]); }
        #pragma unroll
        for (int t = 0; t < 4; ++t) { bf8v A = ldAL(cur, 12 + t); a[0][t] = MF(A, hxn1[0],   a[0][t]); a[1][t] = MF(A, hxn1[1],   a[1][t]); }
        #pragma unroll
        for (int t = 0; t < 4; ++t) { bf8v A = ldAL(cur, 16 + t); a[0][t] = MF(A, msgB[0],   a[0][t]); a[1][t] = MF(A, msgB[1],   a[1][t]); }

        bf8v u0[2] = { packB(a[0], 0, true), packB(a[1], 0, true) };
        bf8v u1[2] = { packB(a[0], 1, true), packB(a[1], 1, true) };

        f4 a2[2][4];
        #pragma unroll
        for (int t = 0; t < 4; ++t) { f4 bv = ldBiasL(cur, 32 + t); a2[0][t] = bv; a2[1][t] = bv; }
        #pragma unroll
        for (int t = 0; t < 4; ++t) { bf8v A = ldAL(cur, 20 + t); a2[0][t] = MF(A, u0[0], a2[0][t]); a2[1][t] = MF(A, u0[1], a2[1][t]); }
        #pragma unroll
        for (int t = 0; t < 4; ++t) { bf8v A = ldAL(cur, 24 + t); a2[0][t] = MF(A, u1[0], a2[0][t]); a2[1][t] = MF(A, u1[1], a2[1][t]); }
        #pragma unroll
        for (int cc = 0; cc < 2; ++cc)
            #pragma unroll
            for (int h = 0; h < 2; ++h) {
                bf8v p = packB(a2[cc], h, true);
                if (m == 0) sB[cc][h] = p;
                else {
                    #pragma unroll
                    for (int j = 0; j < 8; ++j)
                        sB[cc][h][j] = (__bf16)((float)sB[cc][h][j] + (float)p[j]);
                }
            }
        __syncthreads();           // next-phase loads complete + all waves done with cur
    }

    // ======== P3 (bufB): nd MLP -> U; prefetch P4 -> bufA ========
    bf8v uu0[2], uu1[2];
    {
        stageA(bufA, 132, 32);
        f4 a[2][4];
        #pragma unroll
        for (int t = 0; t < 4; ++t) { f4 bv = ldBiasL(bufB, 16 + t); a[0][t] = bv; a[1][t] = bv; }
        #pragma unroll
        for (int t = 0; t < 4; ++t) { bf8v A = ldAL(bufB, t);     a[0][t] = MF(A, sB[0][0], a[0][t]); a[1][t] = MF(A, sB[1][0], a[1][t]); }
        #pragma unroll
        for (int t = 0; t < 4; ++t) { bf8v A = ldAL(bufB, 4 + t); a[0][t] = MF(A, sB[0][1], a[0][t]); a[1][t] = MF(A, sB[1][1], a[1][t]); }
        bf8v w0[2] = { packB(a[0], 0, true), packB(a[1], 0, true) };
        bf8v w1[2] = { packB(a[0], 1, true), packB(a[1], 1, true) };
        f4 a2[2][4];
        #pragma unroll
        for (int t = 0; t < 4; ++t) { f4 bv = ldBiasL(bufB, 20 + t); a2[0][t] = bv; a2[1][t] = bv; }
        #pragma unroll
        for (int t = 0; t < 4; ++t) { bf8v A = ldAL(bufB, 8 + t);  a2[0][t] = MF(A, w0[0], a2[0][t]); a2[1][t] = MF(A, w0[1], a2[1][t]); }
        #pragma unroll
        for (int t = 0; t < 4; ++t) { bf8v A = ldAL(bufB, 12 + t); a2[0][t] = MF(A, w1[0], a2[0][t]); a2[1][t] = MF(A, w1[1], a2[1][t]); }
        uu0[0] = packB(a2[0], 0, true); uu0[1] = packB(a2[1], 0, true);
        uu1[0] = packB(a2[0], 1, true); uu1[1] = packB(a2[1], 1, true);
        __syncthreads();
    }

    // ======== P4 (bufA): GRU-A: gB = bf16(sigm(r) * hg); prefetch P5 -> bufB ========
    bf8v gB[2][2];
    {
        stageA(bufB, 164, 32);
        f4 g0[2][4];
        #pragma unroll
        for (int t = 0; t < 4; ++t) { f4 bv = ldBiasL(bufA, 24 + t); g0[0][t] = bv; g0[1][t] = bv; }
        #pragma unroll
        for (int t = 0; t < 4; ++t) { bf8v A = ldAL(bufA, t);     g0[0][t] = MF(A, hxn0[0], g0[0][t]); g0[1][t] = MF(A, hxn0[1], g0[1][t]); }
        #pragma unroll
        for (int t = 0; t < 4; ++t) { bf8v A = ldAL(bufA, 4 + t); g0[0][t] = MF(A, hxn1[0], g0[0][t]); g0[1][t] = MF(A, hxn1[1], g0[1][t]); }
        f4 rr[2][4];
        #pragma unroll
        for (int t = 0; t < 4; ++t) { f4 bv = ldBiasL(bufA, 28 + t); rr[0][t] = bv; rr[1][t] = bv; }
        #pragma unroll
        for (int t = 0; t < 4; ++t) { bf8v A = ldAL(bufA, 8 + t);  rr[0][t] = MF(A, uu0[0], rr[0][t]); rr[1][t] = MF(A, uu0[1], rr[1][t]); }
        #pragma unroll
        for (int t = 0; t < 4; ++t) { bf8v A = ldAL(bufA, 12 + t); rr[0][t] = MF(A, uu1[0], rr[0][t]); rr[1][t] = MF(A, uu1[1], rr[1][t]); }
        #pragma unroll
        for (int t = 0; t < 4; ++t) { bf8v A = ldAL(bufA, 16 + t); rr[0][t] = MF(A, hxn0[0], rr[0][t]); rr[1][t] = MF(A, hxn0[1], rr[1][t]); }
        #pragma unroll
        for (int t = 0; t < 4; ++t) { bf8v A = ldAL(bufA, 20 + t); rr[0][t] = MF(A, hxn1[0], rr[0][t]); rr[1][t] = MF(A, hxn1[1], rr[1][t]); }
        #pragma unroll
        for (int cc = 0; cc < 2; ++cc)
            #pragma unroll
            for (int t = 0; t < 4; ++t)
                #pragma unroll
                for (int r = 0; r < 4; ++r)
                    gB[cc][t >> 1][(t & 1) * 4 + r] = (__bf16)(sigm(rr[cc][t][r]) * g0[cc][t][r]);
        __syncthreads();
    }

    // ======== P5 (bufB): GRU-B; prefetch P6 -> bufA ========
    bf8v hnB0[2], hnB1[2];
    {
        stageA(bufA, 196, 15);
        // hprev (C layout, f32) issued FIRST: its latency hides under gi MFMAs + tanh
        f4 hpv[2][4];
        #pragma unroll
        for (int cc = 0; cc < 2; ++cc)
            #pragma unroll
            for (int t = 0; t < 4; ++t)
                #pragma unroll
                for (int r = 0; r < 4; ++r)
                    hpv[cc][t][r] = hx[baseH + (16 * t + 4 * s + r) * NPOS + Gn[cc]];

        f4 gi[2][4];
        #pragma unroll
        for (int t = 0; t < 4; ++t) { f4 bv = ldBiasL(bufB, 24 + t); gi[0][t] = bv; gi[1][t] = bv; }
        #pragma unroll
        for (int t = 0; t < 4; ++t) { bf8v A = ldAL(bufB, t);     gi[0][t] = MF(A, uu0[0], gi[0][t]); gi[1][t] = MF(A, uu0[1], gi[1][t]); }
        #pragma unroll
        for (int t = 0; t < 4; ++t) { bf8v A = ldAL(bufB, 4 + t); gi[0][t] = MF(A, uu1[0], gi[0][t]); gi[1][t] = MF(A, uu1[1], gi[1][t]); }
        bf8v nB[2][2];
        #pragma unroll
        for (int cc = 0; cc < 2; ++cc)
            #pragma unroll
            for (int t = 0; t < 4; ++t)
                #pragma unroll
                for (int r = 0; r < 4; ++r)
                    nB[cc][t >> 1][(t & 1) * 4 + r] =
                        (__bf16)tanh_f(gi[cc][t][r] + (float)gB[cc][t >> 1][(t & 1) * 4 + r]);

        f4 zz[2][4];
        #pragma unroll
        for (int t = 0; t < 4; ++t) { f4 bv = ldBiasL(bufB, 28 + t); zz[0][t] = bv; zz[1][t] = bv; }
        #pragma unroll
        for (int t = 0; t < 4; ++t) { bf8v A = ldAL(bufB, 8 + t);  zz[0][t] = MF(A, uu0[0], zz[0][t]); zz[1][t] = MF(A, uu0[1], zz[1][t]); }
        #pragma unroll
        for (int t = 0; t < 4; ++t) { bf8v A = ldAL(bufB, 12 + t); zz[0][t] = MF(A, uu1[0], zz[0][t]); zz[1][t] = MF(A, uu1[1], zz[1][t]); }
        #pragma unroll
        for (int t = 0; t < 4; ++t) { bf8v A = ldAL(bufB, 16 + t); zz[0][t] = MF(A, hxn0[0], zz[0][t]); zz[1][t] = MF(A, hxn0[1], zz[1][t]); }
        #pragma unroll
        for (int t = 0; t < 4; ++t) { bf8v A = ldAL(bufB, 20 + t); zz[0][t] = MF(A, hxn1[0], zz[0][t]); zz[1][t] = MF(A, hxn1[1], zz[1][t]); }

        float* __restrict__ outH = out + NB * 4 * NPOS + baseH;
        #pragma unroll
        for (int cc = 0; cc < 2; ++cc)
            #pragma unroll
            for (int t = 0; t < 4; ++t)
                #pragma unroll
                for (int r = 0; r < 4; ++r) {
                    float z  = sigm(zz[cc][t][r]);
                    float nn = (float)nB[cc][t >> 1][(t & 1) * 4 + r];
                    float hv = nn + z * (hpv[cc][t][r] - nn);
                    outH[(16 * t + 4 * s + r) * NPOS + Gn[cc]] = hv;
                    if (t < 2) hnB0[cc][(t & 1) * 4 + r] = (__bf16)hv;
                    else       hnB1[cc][(t & 1) * 4 + r] = (__bf16)hv;
                }
        __syncthreads();
    }

    // ======== P6 (bufA): decoder ========
    {
        f4 a[2][4];
        #pragma unroll
        for (int t = 0; t < 4; ++t) { f4 bv = ldBiasL(bufA, 10 + t); a[0][t] = bv; a[1][t] = bv; }
        #pragma unroll
        for (int t = 0; t < 4; ++t) { bf8v A = ldAL(bufA, t);     a[0][t] = MF(A, hnB0[0], a[0][t]); a[1][t] = MF(A, hnB0[1], a[1][t]); }
        #pragma unroll
        for (int t = 0; t < 4; ++t) { bf8v A = ldAL(bufA, 4 + t); a[0][t] = MF(A, hnB1[0], a[0][t]); a[1][t] = MF(A, hnB1[1], a[1][t]); }
        bf8v e0[2] = { packB(a[0], 0, true), packB(a[1], 0, true) };
        bf8v e1[2] = { packB(a[0], 1, true), packB(a[1], 1, true) };
        f4 ep[2];
        { f4 bv = ldBiasL(bufA, 14); ep[0] = bv; ep[1] = bv; }
        { bf8v A = ldAL(bufA, 8); ep[0] = MF(A, e0[0], ep[0]); ep[1] = MF(A, e0[1], ep[1]); }
        { bf8v A = ldAL(bufA, 9); ep[0] = MF(A, e1[0], ep[0]); ep[1] = MF(A, e1[1], ep[1]); }
        if (s == 0) {
            #pragma unroll
            for (int cc = 0; cc < 2; ++cc) {
                #pragma unroll
                for (int r = 0; r < 4; ++r) out[baseX + r * NPOS + Gn[cc]] = ep[cc][r];
            }
        }
    }
}

extern "C" void kernel_launch(void* const* d_in, const int* in_sizes, int n_in,
                              void* d_out, int out_size, void* d_ws, size_t ws_size,
                              hipStream_t stream) {
    const float* hx   = (const float*)d_in[0];
    const float* pcm  = (const float*)d_in[1];
    const float* fcm  = (const float*)d_in[2];
    const float* ycm  = (const float*)d_in[3];
    const float* hy   = (const float*)d_in[4];

    prep_kernel<<<dim3(NFRAG), dim3(64), 0, stream>>>(
        (const float*)d_in[5],  (const float*)d_in[6],  (const float*)d_in[7],  (const float*)d_in[8],
        (const float*)d_in[9],  (const float*)d_in[10], (const float*)d_in[11], (const float*)d_in[12],
        (const float*)d_in[13], (const float*)d_in[14], (const float*)d_in[15], (const float*)d_in[16],
        (const float*)d_in[17], (const float*)d_in[18], (const float*)d_in[19], (const float*)d_in[20],
        (const float*)d_in[21], (const float*)d_in[22], (const float*)d_in[23], (const float*)d_in[24],
        (const float*)d_in[25], (const float*)d_in[26], (const float*)d_in[27], (const float*)d_in[28],
        (char*)d_ws);

    kgnn_main<<<dim3(NB * 32), dim3(256), 0, stream>>>(
        hx, pcm, fcm, ycm, hy, (const char*)d_ws, (float*)d_out);
}

// Round 15
// 93.134 us; speedup vs baseline: 1.1045x; 1.1045x over previous
//
#include <hip/hip_runtime.h>

#define NPOS 4096
#define NB   64

typedef __bf16 bf8v __attribute__((ext_vector_type(8)));
typedef float  f4   __attribute__((ext_vector_type(4)));

__device__ __forceinline__ float sigm(float x)   { return 1.0f / (1.0f + __expf(-x)); }
__device__ __forceinline__ float tanh_f(float x) { return 1.0f - 2.0f / (1.0f + __expf(2.0f * x)); }

__device__ __forceinline__ f4 MF(bf8v a, bf8v b, f4 c) {
    return __builtin_amdgcn_mfma_f32_16x16x32_bf16(a, b, c, 0, 0, 0);
}

// async global->LDS, 16B per lane; LDS dest = wave-uniform base + lane*16
__device__ __forceinline__ void gl_lds16(const void* g, void* l) {
    __builtin_amdgcn_global_load_lds(
        (const __attribute__((address_space(1))) void*)g,
        (__attribute__((address_space(3)))       void*)l,
        16, 0, 0);
}

// ---------------- phase-contiguous frag layout in d_ws (1KB frags) ----------------
// (unchanged from R9; PERM layers use k-slot feature kb*32+16*(j>>2)+4*sg+(j&3)
//  so the next layer's B-frag is a lane-local repack of this layer's C regs)
#define NFRAG 211

__global__ __launch_bounds__(64) void prep_kernel(
    const float* __restrict__ pcW1, const float* __restrict__ pcb1, const float* __restrict__ pcW2, const float* __restrict__ pcb2,
    const float* __restrict__ fcW1, const float* __restrict__ fcb1, const float* __restrict__ fcW2, const float* __restrict__ fcb2,
    const float* __restrict__ ycW1, const float* __restrict__ ycb1, const float* __restrict__ ycW2, const float* __restrict__ ycb2,
    const float* __restrict__ ndW1, const float* __restrict__ ndb1, const float* __restrict__ ndW2, const float* __restrict__ ndb2,
    const float* __restrict__ Wih,  const float* __restrict__ bih,  const float* __restrict__ Whh,  const float* __restrict__ bhh,
    const float* __restrict__ dW1,  const float* __restrict__ db1,  const float* __restrict__ dW2,  const float* __restrict__ db2,
    char* __restrict__ ws)
{
    const int f = blockIdx.x, l = threadIdx.x;
    const int sg = l >> 4, c16 = l & 15;
    char* dst = ws + (size_t)f * 1024 + (size_t)l * 16;

    int kind = 0;                 // 0: bf16 weight frag, 1: f32 bias frag
    const float* W = nullptr; const float* B1 = nullptr; const float* B2 = nullptr;
    int t = 0, kb = 0, ncol = 64, coloff = 0, boff = 0, mlp = 0;
    bool msgmask = false, decw2 = false, db2frag = false, perm = false;

    if (f < 108) {
        const int m = f / 36, r = f % 36;
        const float* W1 = (m == 0 ? pcW1 : (m == 1 ? fcW1 : ycW1));
        const float* W2 = (m == 0 ? pcW2 : (m == 1 ? fcW2 : ycW2));
        const float* b1 = (m == 0 ? pcb1 : (m == 1 ? fcb1 : ycb1));
        const float* b2 = (m == 0 ? pcb2 : (m == 1 ? fcb2 : ycb2));
        if (r < 20)      { W = W1; kb = r >> 2; t = r & 3; msgmask = (kb == 4); mlp = m; }
        else if (r < 28) { W = W2; int rr = r - 20; kb = rr >> 2; t = rr & 3; perm = true; }
        else if (r < 32) { kind = 1; B1 = b1; t = r - 28; }
        else             { kind = 1; B1 = b2; t = r - 32; }
    } else if (f < 132) {
        const int r = f - 108;
        if (r < 8)       { W = ndW1; kb = r >> 2; t = r & 3; perm = true; }
        else if (r < 16) { W = ndW2; int rr = r - 8; kb = rr >> 2; t = rr & 3; perm = true; }
        else if (r < 20) { kind = 1; B1 = ndb1; t = r - 16; }
        else             { kind = 1; B1 = ndb2; t = r - 20; }
    } else if (f < 164) {
        const int r = f - 132; ncol = 192;
        if (r < 8)       { W = Whh; coloff = 128; kb = r >> 2; t = r & 3; }
        else if (r < 16) { W = Wih; coloff = 0;   int rr = r - 8;  kb = rr >> 2; t = rr & 3; perm = true; }
        else if (r < 24) { W = Whh; coloff = 0;   int rr = r - 16; kb = rr >> 2; t = rr & 3; }
        else if (r < 28) { kind = 1; B1 = bhh; boff = 128; t = r - 24; }
        else             { kind = 1; B1 = bih; B2 = bhh; boff = 0; t = r - 28; }
    } else if (f < 196) {
        const int r = f - 164; ncol = 192;
        if (r < 8)       { W = Wih; coloff = 128; kb = r >> 2; t = r & 3; perm = true; }
        else if (r < 16) { W = Wih; coloff = 64;  int rr = r - 8;  kb = rr >> 2; t = rr & 3; perm = true; }
        else if (r < 24) { W = Whh; coloff = 64;  int rr = r - 16; kb = rr >> 2; t = rr & 3; }
        else if (r < 28) { kind = 1; B1 = bih; boff = 128; t = r - 24; }
        else             { kind = 1; B1 = bih; B2 = bhh; boff = 64; t = r - 28; }
    } else {
        const int r = f - 196;
        if (r < 8)       { W = dW1; kb = r >> 2; t = r & 3; perm = true; }
        else if (r < 10) { W = dW2; kb = r - 8; t = 0; decw2 = true; perm = true; }
        else if (r < 14) { kind = 1; B1 = db1; t = r - 10; }
        else             { kind = 1; B1 = db2; t = 0; db2frag = true; }
    }

    if (!kind) {
        const int row = 16 * t + c16;
        bf8v v;
        #pragma unroll
        for (int j = 0; j < 8; ++j) {
            const int k = perm ? (kb * 32 + 16 * (j >> 2) + 4 * sg + (j & 3))
                               : (kb * 32 + sg * 8 + j);
            float x;
            if (msgmask) { const int kk = k - 128 - mlp * 4; x = (kk >= 0 && kk < 4) ? W[(128 + kk) * 64 + row] : 0.f; }
            else if (decw2) { x = (row < 4) ? W[k * 4 + row] : 0.f; }
            else { x = W[k * ncol + coloff + row]; }
            v[j] = (__bf16)x;
        }
        *(bf8v*)dst = v;
    } else {
        f4 o;
        #pragma unroll
        for (int r4 = 0; r4 < 4; ++r4) {
            float x;
            if (db2frag) { x = (sg == 0 && t == 0) ? B1[r4] : 0.f; }
            else {
                const int fi = boff + 16 * t + 4 * sg + r4;
                x = B1[fi]; if (B2) x += B2[fi];
            }
            o[r4] = x;
        }
        *(f4*)dst = o;
    }
}

// ---------------- LDS: double-buffered weight phase buffers ----------------
#define WSTRIDE 36864
#define LDSZ    73728      // 2 x 36 frags x 1KB; shared by 8 waves -> 2 blocks/CU

__global__ __launch_bounds__(512, 4) void kgnn_main(
    const float* __restrict__ hx,  const float* __restrict__ pcm,
    const float* __restrict__ fcm, const float* __restrict__ ycm,
    const float* __restrict__ hy,
    const char*  __restrict__ ws,  float* __restrict__ out)
{
    __shared__ __align__(16) char LD[LDSZ];
    char* const bufA = LD;
    char* const bufB = LD + WSTRIDE;
    const int tid  = threadIdx.x;
    const int b    = blockIdx.x >> 5;
    const int tile = blockIdx.x & 31;
    const int n0   = tile * 128;
    const int baseH = b * 64 * NPOS;
    const int baseX = b * 4 * NPOS;

    const int lane = tid & 63, wid = tid >> 6;   // wid 0..7, one 16-pos group per wave
    const int s = lane >> 4, q = lane & 15;
    const int Pv = wid * 16 + q;                 // block-rel position 0..127
    const int Gn = n0 + Pv;

    auto ldTB = [&](const float* __restrict__ T, int gnq, int h) -> bf8v {
        bf8v v;
        #pragma unroll
        for (int j = 0; j < 8; ++j)
            v[j] = (__bf16)T[baseH + (h * 32 + 8 * s + j) * NPOS + gnq];
        return v;
    };
    // lane-local C->B repack (PERM layers): B[h] = {a[2h][0..3], a[2h+1][0..3]}
    auto packB = [&](const f4* aa, int h, bool relu) -> bf8v {
        bf8v v;
        #pragma unroll
        for (int j = 0; j < 8; ++j) {
            float x = aa[2 * h + (j >> 2)][j & 3];
            if (relu) x = fmaxf(x, 0.f);
            v[j] = (__bf16)x;
        }
        return v;
    };

    // ---- hx[n] B-frags (reused across all phases) + message B-frag ----
    bf8v hxn0 = ldTB(hx, Gn, 0);
    bf8v hxn1 = ldTB(hx, Gn, 1);
    bf8v msgB;
    #pragma unroll
    for (int j = 0; j < 8; ++j) {
        const int idx = 8 * s + j;
        float x = 0.f;
        if      (idx < 4)  x = pcm[baseX + idx * NPOS + Gn];
        else if (idx < 8)  x = fcm[baseX + (idx - 4) * NPOS + Gn];
        else if (idx < 12) x = ycm[baseX + (idx - 8) * NPOS + Gn];
        msgB[j] = (__bf16)x;
    }

    // async wave-interleaved staging (8 waves share the copy)
    auto stageA = [&](char* dstbuf, int gbase, int nf) {
        #pragma unroll
        for (int f0 = 0; f0 < 5; ++f0) {
            const int f = f0 * 8 + wid;
            if (f < nf)
                gl_lds16(ws + ((size_t)(gbase + f) << 10) + ((size_t)lane << 4),
                         dstbuf + (f << 10));
        }
    };

    auto ldAL = [&](const char* base, int fl) -> bf8v {
        return *(const bf8v*)(base + (fl << 10) + (lane << 4));
    };
    auto ldBiasL = [&](const char* base, int fl) -> f4 {
        return *(const f4*)(base + (fl << 10) + (lane << 4));
    };

    stageA(bufA, 0, 36);           // P0 -> A
    __syncthreads();               // drains vmcnt (incl. hoisted input loads)

    // ======== P0/P1/P2: pc / fc / yc MLPs ========
    bf8v sB[2];                    // packed bf16 running sum pe+fe+ye
    #pragma unroll
    for (int m = 0; m < 3; ++m) {
        char* cur = (m & 1) ? bufB : bufA;
        char* oth = (m & 1) ? bufA : bufB;
        stageA(oth, (m == 0) ? 36 : (m == 1 ? 72 : 108), (m == 2) ? 24 : 36);   // next phase

        bf8v e0, e1;
        if (m == 0) {
            const int gm = (Gn == 0) ? 0 : Gn - 1;
            e0 = ldTB(hx, gm, 0); e1 = ldTB(hx, gm, 1);
        } else if (m == 1) {
            const int gp = (Gn == NPOS - 1) ? NPOS - 1 : Gn + 1;
            e0 = ldTB(hx, gp, 0); e1 = ldTB(hx, gp, 1);
        } else {
            e0 = ldTB(hy, Gn, 0); e1 = ldTB(hy, Gn, 1);
        }
        f4 a[4];
        #pragma unroll
        for (int t = 0; t < 4; ++t) a[t] = ldBiasL(cur, 28 + t);
        #pragma unroll
        for (int t = 0; t < 4; ++t) a[t] = MF(ldAL(cur, t),      e0,   a[t]);
        #pragma unroll
        for (int t = 0; t < 4; ++t) a[t] = MF(ldAL(cur, 4 + t),  e1,   a[t]);
        #pragma unroll
        for (int t = 0; t < 4; ++t) a[t] = MF(ldAL(cur, 8 + t),  hxn0, a[t]);
        #pragma unroll
        for (int t = 0; t < 4; ++t) a[t] = MF(ldAL(cur, 12 + t), hxn1, a[t]);
        #pragma unroll
        for (int t = 0; t < 4; ++t) a[t] = MF(ldAL(cur, 16 + t), msgB, a[t]);

        bf8v u0 = packB(a, 0, true);
        bf8v u1 = packB(a, 1, true);

        f4 a2[4];
        #pragma unroll
        for (int t = 0; t < 4; ++t) a2[t] = ldBiasL(cur, 32 + t);
        #pragma unroll
        for (int t = 0; t < 4; ++t) a2[t] = MF(ldAL(cur, 20 + t), u0, a2[t]);
        #pragma unroll
        for (int t = 0; t < 4; ++t) a2[t] = MF(ldAL(cur, 24 + t), u1, a2[t]);
        #pragma unroll
        for (int h = 0; h < 2; ++h) {
            bf8v p = packB(a2, h, true);
            if (m == 0) sB[h] = p;
            else {
                #pragma unroll
                for (int j = 0; j < 8; ++j)
                    sB[h][j] = (__bf16)((float)sB[h][j] + (float)p[j]);
            }
        }
        __syncthreads();           // next-phase loads complete + all waves done with cur
    }

    // ======== P3 (bufB): nd MLP -> U; prefetch P4 -> bufA ========
    bf8v uu0, uu1;
    {
        stageA(bufA, 132, 32);
        f4 a[4];
        #pragma unroll
        for (int t = 0; t < 4; ++t) a[t] = ldBiasL(bufB, 16 + t);
        #pragma unroll
        for (int t = 0; t < 4; ++t) a[t] = MF(ldAL(bufB, t),     sB[0], a[t]);
        #pragma unroll
        for (int t = 0; t < 4; ++t) a[t] = MF(ldAL(bufB, 4 + t), sB[1], a[t]);
        bf8v w0 = packB(a, 0, true);
        bf8v w1 = packB(a, 1, true);
        f4 a2[4];
        #pragma unroll
        for (int t = 0; t < 4; ++t) a2[t] = ldBiasL(bufB, 20 + t);
        #pragma unroll
        for (int t = 0; t < 4; ++t) a2[t] = MF(ldAL(bufB, 8 + t),  w0, a2[t]);
        #pragma unroll
        for (int t = 0; t < 4; ++t) a2[t] = MF(ldAL(bufB, 12 + t), w1, a2[t]);
        uu0 = packB(a2, 0, true);
        uu1 = packB(a2, 1, true);
        __syncthreads();
    }

    // ======== P4 (bufA): GRU-A: gB = bf16(sigm(r) * hg); prefetch P5 -> bufB ========
    bf8v gB;                       // n-gate precursor packed: [t>>1][(t&1)*4+r] layout folded
    bf8v gB2;
    {
        stageA(bufB, 164, 32);
        f4 g0[4];
        #pragma unroll
        for (int t = 0; t < 4; ++t) g0[t] = ldBiasL(bufA, 24 + t);
        #pragma unroll
        for (int t = 0; t < 4; ++t) g0[t] = MF(ldAL(bufA, t),     hxn0, g0[t]);
        #pragma unroll
        for (int t = 0; t < 4; ++t) g0[t] = MF(ldAL(bufA, 4 + t), hxn1, g0[t]);
        f4 rr[4];
        #pragma unroll
        for (int t = 0; t < 4; ++t) rr[t] = ldBiasL(bufA, 28 + t);
        #pragma unroll
        for (int t = 0; t < 4; ++t) rr[t] = MF(ldAL(bufA, 8 + t),  uu0,  rr[t]);
        #pragma unroll
        for (int t = 0; t < 4; ++t) rr[t] = MF(ldAL(bufA, 12 + t), uu1,  rr[t]);
        #pragma unroll
        for (int t = 0; t < 4; ++t) rr[t] = MF(ldAL(bufA, 16 + t), hxn0, rr[t]);
        #pragma unroll
        for (int t = 0; t < 4; ++t) rr[t] = MF(ldAL(bufA, 20 + t), hxn1, rr[t]);
        #pragma unroll
        for (int t = 0; t < 4; ++t)
            #pragma unroll
            for (int r = 0; r < 4; ++r) {
                float v = sigm(rr[t][r]) * g0[t][r];
                if (t < 2) gB[(t & 1) * 4 + r]  = (__bf16)v;
                else       gB2[(t & 1) * 4 + r] = (__bf16)v;
            }
        __syncthreads();
    }

    // ======== P5 (bufB): GRU-B; prefetch P6 -> bufA ========
    bf8v hnB0, hnB1;
    {
        stageA(bufA, 196, 15);
        f4 gi[4];
        #pragma unroll
        for (int t = 0; t < 4; ++t) gi[t] = ldBiasL(bufB, 24 + t);
        #pragma unroll
        for (int t = 0; t < 4; ++t) gi[t] = MF(ldAL(bufB, t),     uu0, gi[t]);
        #pragma unroll
        for (int t = 0; t < 4; ++t) gi[t] = MF(ldAL(bufB, 4 + t), uu1, gi[t]);
        bf8v nB0, nB1;
        #pragma unroll
        for (int t = 0; t < 4; ++t)
            #pragma unroll
            for (int r = 0; r < 4; ++r) {
                float gv = (t < 2) ? (float)gB[(t & 1) * 4 + r] : (float)gB2[(t & 1) * 4 + r];
                float v = tanh_f(gi[t][r] + gv);
                if (t < 2) nB0[(t & 1) * 4 + r] = (__bf16)v;
                else       nB1[(t & 1) * 4 + r] = (__bf16)v;
            }

        // hprev (C layout, f32): latency hides under the zz MFMAs
        f4 hpv[4];
        #pragma unroll
        for (int t = 0; t < 4; ++t)
            #pragma unroll
            for (int r = 0; r < 4; ++r)
                hpv[t][r] = hx[baseH + (16 * t + 4 * s + r) * NPOS + Gn];

        f4 zz[4];
        #pragma unroll
        for (int t = 0; t < 4; ++t) zz[t] = ldBiasL(bufB, 28 + t);
        #pragma unroll
        for (int t = 0; t < 4; ++t) zz[t] = MF(ldAL(bufB, 8 + t),  uu0,  zz[t]);
        #pragma unroll
        for (int t = 0; t < 4; ++t) zz[t] = MF(ldAL(bufB, 12 + t), uu1,  zz[t]);
        #pragma unroll
        for (int t = 0; t < 4; ++t) zz[t] = MF(ldAL(bufB, 16 + t), hxn0, zz[t]);
        #pragma unroll
        for (int t = 0; t < 4; ++t) zz[t] = MF(ldAL(bufB, 20 + t), hxn1, zz[t]);

        float* __restrict__ outH = out + NB * 4 * NPOS + baseH;
        #pragma unroll
        for (int t = 0; t < 4; ++t)
            #pragma unroll
            for (int r = 0; r < 4; ++r) {
                float z  = sigm(zz[t][r]);
                float nn = (t < 2) ? (float)nB0[(t & 1) * 4 + r] : (float)nB1[(t & 1) * 4 + r];
                float hv = nn + z * (hpv[t][r] - nn);
                outH[(16 * t + 4 * s + r) * NPOS + Gn] = hv;
                if (t < 2) hnB0[(t & 1) * 4 + r] = (__bf16)hv;
                else       hnB1[(t & 1) * 4 + r] = (__bf16)hv;
            }
        __syncthreads();
    }

    // ======== P6 (bufA): decoder ========
    {
        f4 a[4];
        #pragma unroll
        for (int t = 0; t < 4; ++t) a[t] = ldBiasL(bufA, 10 + t);
        #pragma unroll
        for (int t = 0; t < 4; ++t) a[t] = MF(ldAL(bufA, t),     hnB0, a[t]);
        #pragma unroll
        for (int t = 0; t < 4; ++t) a[t] = MF(ldAL(bufA, 4 + t), hnB1, a[t]);
        bf8v e0 = packB(a, 0, true);
        bf8v e1 = packB(a, 1, true);
        f4 ep = ldBiasL(bufA, 14);
        ep = MF(ldAL(bufA, 8), e0, ep);
        ep = MF(ldAL(bufA, 9), e1, ep);
        if (s == 0) {
            #pragma unroll
            for (int r = 0; r < 4; ++r) out[baseX + r * NPOS + Gn] = ep[r];
        }
    }
}

extern "C" void kernel_launch(void* const* d_in, const int* in_sizes, int n_in,
                              void* d_out, int out_size, void* d_ws, size_t ws_size,
                              hipStream_t stream) {
    const float* hx   = (const float*)d_in[0];
    const float* pcm  = (const float*)d_in[1];
    const float* fcm  = (const float*)d_in[2];
    const float* ycm  = (const float*)d_in[3];
    const float* hy   = (const float*)d_in[4];

    prep_kernel<<<dim3(NFRAG), dim3(64), 0, stream>>>(
        (const float*)d_in[5],  (const float*)d_in[6],  (const float*)d_in[7],  (const float*)d_in[8],
        (const float*)d_in[9],  (const float*)d_in[10], (const float*)d_in[11], (const float*)d_in[12],
        (const float*)d_in[13], (const float*)d_in[14], (const float*)d_in[15], (const float*)d_in[16],
        (const float*)d_in[17], (const float*)d_in[18], (const float*)d_in[19], (const float*)d_in[20],
        (const float*)d_in[21], (const float*)d_in[22], (const float*)d_in[23], (const float*)d_in[24],
        (const float*)d_in[25], (const float*)d_in[26], (const float*)d_in[27], (const float*)d_in[28],
        (char*)d_ws);

    kgnn_main<<<dim3(NB * 32), dim3(512), 0, stream>>>(
        hx, pcm, fcm, ycm, hy, (const char*)d_ws, (float*)d_out);
}

// Round 16
// 90.487 us; speedup vs baseline: 1.1368x; 1.0293x over previous
//
#include <hip/hip_runtime.h>

#define NPOS 4096
#define NB   64

typedef __bf16 bf8v __attribute__((ext_vector_type(8)));
typedef float  f4   __attribute__((ext_vector_type(4)));

__device__ __forceinline__ float sigm(float x)   { return 1.0f / (1.0f + __expf(-x)); }
__device__ __forceinline__ float tanh_f(float x) { return 1.0f - 2.0f / (1.0f + __expf(2.0f * x)); }

__device__ __forceinline__ f4 MF(bf8v a, bf8v b, f4 c) {
    return __builtin_amdgcn_mfma_f32_16x16x32_bf16(a, b, c, 0, 0, 0);
}
#define PRIO_HI() __builtin_amdgcn_s_setprio(1)
#define PRIO_LO() __builtin_amdgcn_s_setprio(0)

// async global->LDS, 16B per lane; LDS dest = wave-uniform base + lane*16
__device__ __forceinline__ void gl_lds16(const void* g, void* l) {
    __builtin_amdgcn_global_load_lds(
        (const __attribute__((address_space(1))) void*)g,
        (__attribute__((address_space(3)))       void*)l,
        16, 0, 0);
}

// ---------------- phase-contiguous frag layout in d_ws (1KB frags) ----------------
// (unchanged from R9; PERM layers use k-slot feature kb*32+16*(j>>2)+4*sg+(j&3)
//  so the next layer's B-frag is a lane-local repack of this layer's C regs)
#define NFRAG 211

__global__ __launch_bounds__(64) void prep_kernel(
    const float* __restrict__ pcW1, const float* __restrict__ pcb1, const float* __restrict__ pcW2, const float* __restrict__ pcb2,
    const float* __restrict__ fcW1, const float* __restrict__ fcb1, const float* __restrict__ fcW2, const float* __restrict__ fcb2,
    const float* __restrict__ ycW1, const float* __restrict__ ycb1, const float* __restrict__ ycW2, const float* __restrict__ ycb2,
    const float* __restrict__ ndW1, const float* __restrict__ ndb1, const float* __restrict__ ndW2, const float* __restrict__ ndb2,
    const float* __restrict__ Wih,  const float* __restrict__ bih,  const float* __restrict__ Whh,  const float* __restrict__ bhh,
    const float* __restrict__ dW1,  const float* __restrict__ db1,  const float* __restrict__ dW2,  const float* __restrict__ db2,
    char* __restrict__ ws)
{
    const int f = blockIdx.x, l = threadIdx.x;
    const int sg = l >> 4, c16 = l & 15;
    char* dst = ws + (size_t)f * 1024 + (size_t)l * 16;

    int kind = 0;                 // 0: bf16 weight frag, 1: f32 bias frag
    const float* W = nullptr; const float* B1 = nullptr; const float* B2 = nullptr;
    int t = 0, kb = 0, ncol = 64, coloff = 0, boff = 0, mlp = 0;
    bool msgmask = false, decw2 = false, db2frag = false, perm = false;

    if (f < 108) {
        const int m = f / 36, r = f % 36;
        const float* W1 = (m == 0 ? pcW1 : (m == 1 ? fcW1 : ycW1));
        const float* W2 = (m == 0 ? pcW2 : (m == 1 ? fcW2 : ycW2));
        const float* b1 = (m == 0 ? pcb1 : (m == 1 ? fcb1 : ycb1));
        const float* b2 = (m == 0 ? pcb2 : (m == 1 ? fcb2 : ycb2));
        if (r < 20)      { W = W1; kb = r >> 2; t = r & 3; msgmask = (kb == 4); mlp = m; }
        else if (r < 28) { W = W2; int rr = r - 20; kb = rr >> 2; t = rr & 3; perm = true; }
        else if (r < 32) { kind = 1; B1 = b1; t = r - 28; }
        else             { kind = 1; B1 = b2; t = r - 32; }
    } else if (f < 132) {
        const int r = f - 108;
        if (r < 8)       { W = ndW1; kb = r >> 2; t = r & 3; perm = true; }
        else if (r < 16) { W = ndW2; int rr = r - 8; kb = rr >> 2; t = rr & 3; perm = true; }
        else if (r < 20) { kind = 1; B1 = ndb1; t = r - 16; }
        else             { kind = 1; B1 = ndb2; t = r - 20; }
    } else if (f < 164) {
        const int r = f - 132; ncol = 192;
        if (r < 8)       { W = Whh; coloff = 128; kb = r >> 2; t = r & 3; }
        else if (r < 16) { W = Wih; coloff = 0;   int rr = r - 8;  kb = rr >> 2; t = rr & 3; perm = true; }
        else if (r < 24) { W = Whh; coloff = 0;   int rr = r - 16; kb = rr >> 2; t = rr & 3; }
        else if (r < 28) { kind = 1; B1 = bhh; boff = 128; t = r - 24; }
        else             { kind = 1; B1 = bih; B2 = bhh; boff = 0; t = r - 28; }
    } else if (f < 196) {
        const int r = f - 164; ncol = 192;
        if (r < 8)       { W = Wih; coloff = 128; kb = r >> 2; t = r & 3; perm = true; }
        else if (r < 16) { W = Wih; coloff = 64;  int rr = r - 8;  kb = rr >> 2; t = rr & 3; perm = true; }
        else if (r < 24) { W = Whh; coloff = 64;  int rr = r - 16; kb = rr >> 2; t = rr & 3; }
        else if (r < 28) { kind = 1; B1 = bih; boff = 128; t = r - 24; }
        else             { kind = 1; B1 = bih; B2 = bhh; boff = 64; t = r - 28; }
    } else {
        const int r = f - 196;
        if (r < 8)       { W = dW1; kb = r >> 2; t = r & 3; perm = true; }
        else if (r < 10) { W = dW2; kb = r - 8; t = 0; decw2 = true; perm = true; }
        else if (r < 14) { kind = 1; B1 = db1; t = r - 10; }
        else             { kind = 1; B1 = db2; t = 0; db2frag = true; }
    }

    if (!kind) {
        const int row = 16 * t + c16;
        bf8v v;
        #pragma unroll
        for (int j = 0; j < 8; ++j) {
            const int k = perm ? (kb * 32 + 16 * (j >> 2) + 4 * sg + (j & 3))
                               : (kb * 32 + sg * 8 + j);
            float x;
            if (msgmask) { const int kk = k - 128 - mlp * 4; x = (kk >= 0 && kk < 4) ? W[(128 + kk) * 64 + row] : 0.f; }
            else if (decw2) { x = (row < 4) ? W[k * 4 + row] : 0.f; }
            else { x = W[k * ncol + coloff + row]; }
            v[j] = (__bf16)x;
        }
        *(bf8v*)dst = v;
    } else {
        f4 o;
        #pragma unroll
        for (int r4 = 0; r4 < 4; ++r4) {
            float x;
            if (db2frag) { x = (sg == 0 && t == 0) ? B1[r4] : 0.f; }
            else {
                const int fi = boff + 16 * t + 4 * sg + r4;
                x = B1[fi]; if (B2) x += B2[fi];
            }
            o[r4] = x;
        }
        *(f4*)dst = o;
    }
}

// ---------------- LDS: double-buffered weight phase buffers ----------------
#define WSTRIDE 36864
#define LDSZ    73728      // 2 x 36 frags x 1KB; shared by 8 waves -> 2 blocks/CU

__global__ __launch_bounds__(512, 4) void kgnn_main(
    const float* __restrict__ hx,  const float* __restrict__ pcm,
    const float* __restrict__ fcm, const float* __restrict__ ycm,
    const float* __restrict__ hy,
    const char*  __restrict__ ws,  float* __restrict__ out)
{
    __shared__ __align__(16) char LD[LDSZ];
    char* const bufA = LD;
    char* const bufB = LD + WSTRIDE;
    const int tid  = threadIdx.x;
    const int b    = blockIdx.x >> 5;
    const int tile = blockIdx.x & 31;
    const int n0   = tile * 128;
    const int baseH = b * 64 * NPOS;
    const int baseX = b * 4 * NPOS;

    const int lane = tid & 63, wid = tid >> 6;   // wid 0..7, one 16-pos group per wave
    const int s = lane >> 4, q = lane & 15;
    const int Pv = wid * 16 + q;                 // block-rel position 0..127
    const int Gn = n0 + Pv;

    auto ldTB = [&](const float* __restrict__ T, int gnq, int h) -> bf8v {
        bf8v v;
        #pragma unroll
        for (int j = 0; j < 8; ++j)
            v[j] = (__bf16)T[baseH + (h * 32 + 8 * s + j) * NPOS + gnq];
        return v;
    };
    // lane-local C->B repack (PERM layers): B[h] = {a[2h][0..3], a[2h+1][0..3]}
    auto packB = [&](const f4* aa, int h, bool relu) -> bf8v {
        bf8v v;
        #pragma unroll
        for (int j = 0; j < 8; ++j) {
            float x = aa[2 * h + (j >> 2)][j & 3];
            if (relu) x = fmaxf(x, 0.f);
            v[j] = (__bf16)x;
        }
        return v;
    };

    // ---- hx[n] B-frags (reused across all phases) + message B-frag ----
    bf8v hxn0 = ldTB(hx, Gn, 0);
    bf8v hxn1 = ldTB(hx, Gn, 1);
    bf8v msgB;
    #pragma unroll
    for (int j = 0; j < 8; ++j) {
        const int idx = 8 * s + j;
        float x = 0.f;
        if      (idx < 4)  x = pcm[baseX + idx * NPOS + Gn];
        else if (idx < 8)  x = fcm[baseX + (idx - 4) * NPOS + Gn];
        else if (idx < 12) x = ycm[baseX + (idx - 8) * NPOS + Gn];
        msgB[j] = (__bf16)x;
    }

    // async wave-interleaved staging (8 waves share the copy)
    auto stageA = [&](char* dstbuf, int gbase, int nf) {
        #pragma unroll
        for (int f0 = 0; f0 < 5; ++f0) {
            const int f = f0 * 8 + wid;
            if (f < nf)
                gl_lds16(ws + ((size_t)(gbase + f) << 10) + ((size_t)lane << 4),
                         dstbuf + (f << 10));
        }
    };

    auto ldAL = [&](const char* base, int fl) -> bf8v {
        return *(const bf8v*)(base + (fl << 10) + (lane << 4));
    };
    auto ldBiasL = [&](const char* base, int fl) -> f4 {
        return *(const f4*)(base + (fl << 10) + (lane << 4));
    };

    stageA(bufA, 0, 36);           // P0 -> A
    __syncthreads();               // drains vmcnt (incl. hoisted input loads)

    // ======== P0/P1/P2: pc / fc / yc MLPs ========
    bf8v sB[2];                    // packed bf16 running sum pe+fe+ye
    #pragma unroll
    for (int m = 0; m < 3; ++m) {
        char* cur = (m & 1) ? bufB : bufA;
        char* oth = (m & 1) ? bufA : bufB;
        stageA(oth, (m == 0) ? 36 : (m == 1 ? 72 : 108), (m == 2) ? 24 : 36);   // next phase

        bf8v e0, e1;
        if (m == 0) {
            const int gm = (Gn == 0) ? 0 : Gn - 1;
            e0 = ldTB(hx, gm, 0); e1 = ldTB(hx, gm, 1);
        } else if (m == 1) {
            const int gp = (Gn == NPOS - 1) ? NPOS - 1 : Gn + 1;
            e0 = ldTB(hx, gp, 0); e1 = ldTB(hx, gp, 1);
        } else {
            e0 = ldTB(hy, Gn, 0); e1 = ldTB(hy, Gn, 1);
        }
        f4 a[4];
        #pragma unroll
        for (int t = 0; t < 4; ++t) a[t] = ldBiasL(cur, 28 + t);
        PRIO_HI();
        #pragma unroll
        for (int t = 0; t < 4; ++t) a[t] = MF(ldAL(cur, t),      e0,   a[t]);
        #pragma unroll
        for (int t = 0; t < 4; ++t) a[t] = MF(ldAL(cur, 4 + t),  e1,   a[t]);
        #pragma unroll
        for (int t = 0; t < 4; ++t) a[t] = MF(ldAL(cur, 8 + t),  hxn0, a[t]);
        #pragma unroll
        for (int t = 0; t < 4; ++t) a[t] = MF(ldAL(cur, 12 + t), hxn1, a[t]);
        #pragma unroll
        for (int t = 0; t < 4; ++t) a[t] = MF(ldAL(cur, 16 + t), msgB, a[t]);
        PRIO_LO();

        bf8v u0 = packB(a, 0, true);
        bf8v u1 = packB(a, 1, true);

        f4 a2[4];
        #pragma unroll
        for (int t = 0; t < 4; ++t) a2[t] = ldBiasL(cur, 32 + t);
        PRIO_HI();
        #pragma unroll
        for (int t = 0; t < 4; ++t) a2[t] = MF(ldAL(cur, 20 + t), u0, a2[t]);
        #pragma unroll
        for (int t = 0; t < 4; ++t) a2[t] = MF(ldAL(cur, 24 + t), u1, a2[t]);
        PRIO_LO();
        #pragma unroll
        for (int h = 0; h < 2; ++h) {
            bf8v p = packB(a2, h, true);
            if (m == 0) sB[h] = p;
            else {
                #pragma unroll
                for (int j = 0; j < 8; ++j)
                    sB[h][j] = (__bf16)((float)sB[h][j] + (float)p[j]);
            }
        }
        __syncthreads();           // next-phase loads complete + all waves done with cur
    }

    // ======== P3 (bufB): nd MLP -> U; prefetch P4 -> bufA ========
    bf8v uu0, uu1;
    {
        stageA(bufA, 132, 32);
        f4 a[4];
        #pragma unroll
        for (int t = 0; t < 4; ++t) a[t] = ldBiasL(bufB, 16 + t);
        PRIO_HI();
        #pragma unroll
        for (int t = 0; t < 4; ++t) a[t] = MF(ldAL(bufB, t),     sB[0], a[t]);
        #pragma unroll
        for (int t = 0; t < 4; ++t) a[t] = MF(ldAL(bufB, 4 + t), sB[1], a[t]);
        PRIO_LO();
        bf8v w0 = packB(a, 0, true);
        bf8v w1 = packB(a, 1, true);
        f4 a2[4];
        #pragma unroll
        for (int t = 0; t < 4; ++t) a2[t] = ldBiasL(bufB, 20 + t);
        PRIO_HI();
        #pragma unroll
        for (int t = 0; t < 4; ++t) a2[t] = MF(ldAL(bufB, 8 + t),  w0, a2[t]);
        #pragma unroll
        for (int t = 0; t < 4; ++t) a2[t] = MF(ldAL(bufB, 12 + t), w1, a2[t]);
        PRIO_LO();
        uu0 = packB(a2, 0, true);
        uu1 = packB(a2, 1, true);
        __syncthreads();
    }

    // ======== P4 (bufA): GRU-A: gB = bf16(sigm(r) * hg); prefetch P5 -> bufB ========
    bf8v gB, gB2;
    {
        stageA(bufB, 164, 32);
        f4 g0[4];
        #pragma unroll
        for (int t = 0; t < 4; ++t) g0[t] = ldBiasL(bufA, 24 + t);
        PRIO_HI();
        #pragma unroll
        for (int t = 0; t < 4; ++t) g0[t] = MF(ldAL(bufA, t),     hxn0, g0[t]);
        #pragma unroll
        for (int t = 0; t < 4; ++t) g0[t] = MF(ldAL(bufA, 4 + t), hxn1, g0[t]);
        PRIO_LO();
        f4 rr[4];
        #pragma unroll
        for (int t = 0; t < 4; ++t) rr[t] = ldBiasL(bufA, 28 + t);
        PRIO_HI();
        #pragma unroll
        for (int t = 0; t < 4; ++t) rr[t] = MF(ldAL(bufA, 8 + t),  uu0,  rr[t]);
        #pragma unroll
        for (int t = 0; t < 4; ++t) rr[t] = MF(ldAL(bufA, 12 + t), uu1,  rr[t]);
        #pragma unroll
        for (int t = 0; t < 4; ++t) rr[t] = MF(ldAL(bufA, 16 + t), hxn0, rr[t]);
        #pragma unroll
        for (int t = 0; t < 4; ++t) rr[t] = MF(ldAL(bufA, 20 + t), hxn1, rr[t]);
        PRIO_LO();
        #pragma unroll
        for (int t = 0; t < 4; ++t)
            #pragma unroll
            for (int r = 0; r < 4; ++r) {
                float v = sigm(rr[t][r]) * g0[t][r];
                if (t < 2) gB[(t & 1) * 4 + r]  = (__bf16)v;
                else       gB2[(t & 1) * 4 + r] = (__bf16)v;
            }
        __syncthreads();
    }

    // ======== P5 (bufB): GRU-B; prefetch P6 -> bufA ========
    bf8v hnB0, hnB1;
    {
        stageA(bufA, 196, 15);
        f4 gi[4];
        #pragma unroll
        for (int t = 0; t < 4; ++t) gi[t] = ldBiasL(bufB, 24 + t);
        PRIO_HI();
        #pragma unroll
        for (int t = 0; t < 4; ++t) gi[t] = MF(ldAL(bufB, t),     uu0, gi[t]);
        #pragma unroll
        for (int t = 0; t < 4; ++t) gi[t] = MF(ldAL(bufB, 4 + t), uu1, gi[t]);
        PRIO_LO();
        bf8v nB0, nB1;
        #pragma unroll
        for (int t = 0; t < 4; ++t)
            #pragma unroll
            for (int r = 0; r < 4; ++r) {
                float gv = (t < 2) ? (float)gB[(t & 1) * 4 + r] : (float)gB2[(t & 1) * 4 + r];
                float v = tanh_f(gi[t][r] + gv);
                if (t < 2) nB0[(t & 1) * 4 + r] = (__bf16)v;
                else       nB1[(t & 1) * 4 + r] = (__bf16)v;
            }

        // hprev (C layout, f32): latency hides under the zz MFMAs
        f4 hpv[4];
        #pragma unroll
        for (int t = 0; t < 4; ++t)
            #pragma unroll
            for (int r = 0; r < 4; ++r)
                hpv[t][r] = hx[baseH + (16 * t + 4 * s + r) * NPOS + Gn];

        f4 zz[4];
        #pragma unroll
        for (int t = 0; t < 4; ++t) zz[t] = ldBiasL(bufB, 28 + t);
        PRIO_HI();
        #pragma unroll
        for (int t = 0; t < 4; ++t) zz[t] = MF(ldAL(bufB, 8 + t),  uu0,  zz[t]);
        #pragma unroll
        for (int t = 0; t < 4; ++t) zz[t] = MF(ldAL(bufB, 12 + t), uu1,  zz[t]);
        #pragma unroll
        for (int t = 0; t < 4; ++t) zz[t] = MF(ldAL(bufB, 16 + t), hxn0, zz[t]);
        #pragma unroll
        for (int t = 0; t < 4; ++t) zz[t] = MF(ldAL(bufB, 20 + t), hxn1, zz[t]);
        PRIO_LO();

        float* __restrict__ outH = out + NB * 4 * NPOS + baseH;
        #pragma unroll
        for (int t = 0; t < 4; ++t)
            #pragma unroll
            for (int r = 0; r < 4; ++r) {
                float z  = sigm(zz[t][r]);
                float nn = (t < 2) ? (float)nB0[(t & 1) * 4 + r] : (float)nB1[(t & 1) * 4 + r];
                float hv = nn + z * (hpv[t][r] - nn);
                outH[(16 * t + 4 * s + r) * NPOS + Gn] = hv;
                if (t < 2) hnB0[(t & 1) * 4 + r] = (__bf16)hv;
                else       hnB1[(t & 1) * 4 + r] = (__bf16)hv;
            }
        __syncthreads();
    }

    // ======== P6 (bufA): decoder ========
    {
        f4 a[4];
        #pragma unroll
        for (int t = 0; t < 4; ++t) a[t] = ldBiasL(bufA, 10 + t);
        PRIO_HI();
        #pragma unroll
        for (int t = 0; t < 4; ++t) a[t] = MF(ldAL(bufA, t),     hnB0, a[t]);
        #pragma unroll
        for (int t = 0; t < 4; ++t) a[t] = MF(ldAL(bufA, 4 + t), hnB1, a[t]);
        PRIO_LO();
        bf8v e0 = packB(a, 0, true);
        bf8v e1 = packB(a, 1, true);
        f4 ep = ldBiasL(bufA, 14);
        PRIO_HI();
        ep = MF(ldAL(bufA, 8), e0, ep);
        ep = MF(ldAL(bufA, 9), e1, ep);
        PRIO_LO();
        if (s == 0) {
            #pragma unroll
            for (int r = 0; r < 4; ++r) out[baseX + r * NPOS + Gn] = ep[r];
        }
    }
}

extern "C" void kernel_launch(void* const* d_in, const int* in_sizes, int n_in,
                              void* d_out, int out_size, void* d_ws, size_t ws_size,
                              hipStream_t stream) {
    const float* hx   = (const float*)d_in[0];
    const float* pcm  = (const float*)d_in[1];
    const float* fcm  = (const float*)d_in[2];
    const float* ycm  = (const float*)d_in[3];
    const float* hy   = (const float*)d_in[4];

    prep_kernel<<<dim3(NFRAG), dim3(64), 0, stream>>>(
        (const float*)d_in[5],  (const float*)d_in[6],  (const float*)d_in[7],  (const float*)d_in[8],
        (const float*)d_in[9],  (const float*)d_in[10], (const float*)d_in[11], (const float*)d_in[12],
        (const float*)d_in[13], (const float*)d_in[14], (const float*)d_in[15], (const float*)d_in[16],
        (const float*)d_in[17], (const float*)d_in[18], (const float*)d_in[19], (const float*)d_in[20],
        (const float*)d_in[21], (const float*)d_in[22], (const float*)d_in[23], (const float*)d_in[24],
        (const float*)d_in[25], (const float*)d_in[26], (const float*)d_in[27], (const float*)d_in[28],
        (char*)d_ws);

    kgnn_main<<<dim3(NB * 32), dim3(512), 0, stream>>>(
        hx, pcm, fcm, ycm, hy, (const char*)d_ws, (float*)d_out);
}